// Round 5
// baseline (722.152 us; speedup 1.0000x reference)
//
#include <hip/hip_runtime.h>
#include <math.h>

#define IMG 800.0f
#define SCORE_TH 0.25f
#define NMS_TH 0.5f
#define MAXDET 100
#define BBOX_CLIP 4.135166556742356f /* log(1000/16) */

constexpr int kB = 16;
constexpr int kN = 4000;
constexpr int kD = 1024;

typedef unsigned long long ull;

// ---------------------------------------------------------------------------
// Kernel 1: fused head matmul (6 needed channels only) + softmax + box decode.
// One wave per row; per-lane weight slice held in registers (24 float4).
// ---------------------------------------------------------------------------
__global__ __launch_bounds__(256, 2) void head_kernel(
    const float* __restrict__ feats, const float* __restrict__ proposals,
    const float* __restrict__ Wc, const float* __restrict__ bc,
    const float* __restrict__ Wb, const float* __restrict__ bb,
    float* __restrict__ out, float* __restrict__ ws_scores,
    float* __restrict__ ws_boxes) {
  const int lane = threadIdx.x & 63;
  const int waveId = (blockIdx.x * blockDim.x + threadIdx.x) >> 6;
  const int nWaves = (gridDim.x * blockDim.x) >> 6;

  const float4* Wc4 = (const float4*)Wc;  // (2,1024) -> 2*256 float4
  const float4* Wb4 = (const float4*)Wb;  // (8,1024) -> 8*256 float4
  float4 w0[4], w1[4], w4[4], w5[4], w6[4], w7[4];
#pragma unroll
  for (int ch = 0; ch < 4; ++ch) {
    int idx = ch * 64 + lane;
    w0[ch] = Wc4[0 * 256 + idx];
    w1[ch] = Wc4[1 * 256 + idx];
    w4[ch] = Wb4[4 * 256 + idx];
    w5[ch] = Wb4[5 * 256 + idx];
    w6[ch] = Wb4[6 * 256 + idx];
    w7[ch] = Wb4[7 * 256 + idx];
  }
  const float bc0 = bc[0], bc1 = bc[1];
  const float bb4 = bb[4], bb5 = bb[5], bb6 = bb[6], bb7 = bb[7];

  const int R = kB * kN;
  for (int row = waveId; row < R; row += nWaves) {
    const float4* F = (const float4*)(feats + (size_t)row * kD);
    float a0 = 0.f, a1 = 0.f, a4 = 0.f, a5 = 0.f, a6 = 0.f, a7 = 0.f;
#pragma unroll
    for (int ch = 0; ch < 4; ++ch) {
      float4 f = F[ch * 64 + lane];
      a0 = fmaf(f.x, w0[ch].x, fmaf(f.y, w0[ch].y, fmaf(f.z, w0[ch].z, fmaf(f.w, w0[ch].w, a0))));
      a1 = fmaf(f.x, w1[ch].x, fmaf(f.y, w1[ch].y, fmaf(f.z, w1[ch].z, fmaf(f.w, w1[ch].w, a1))));
      a4 = fmaf(f.x, w4[ch].x, fmaf(f.y, w4[ch].y, fmaf(f.z, w4[ch].z, fmaf(f.w, w4[ch].w, a4))));
      a5 = fmaf(f.x, w5[ch].x, fmaf(f.y, w5[ch].y, fmaf(f.z, w5[ch].z, fmaf(f.w, w5[ch].w, a5))));
      a6 = fmaf(f.x, w6[ch].x, fmaf(f.y, w6[ch].y, fmaf(f.z, w6[ch].z, fmaf(f.w, w6[ch].w, a6))));
      a7 = fmaf(f.x, w7[ch].x, fmaf(f.y, w7[ch].y, fmaf(f.z, w7[ch].z, fmaf(f.w, w7[ch].w, a7))));
    }
#pragma unroll
    for (int off = 32; off; off >>= 1) {
      a0 += __shfl_xor(a0, off);
      a1 += __shfl_xor(a1, off);
      a4 += __shfl_xor(a4, off);
      a5 += __shfl_xor(a5, off);
      a6 += __shfl_xor(a6, off);
      a7 += __shfl_xor(a7, off);
    }
    if (lane == 0) {
      float l0 = a0 + bc0, l1 = a1 + bc1;
      float score = 1.0f / (1.0f + __expf(l0 - l1));
      float sth = score > SCORE_TH ? score : 0.0f;

      float4 p = ((const float4*)proposals)[row];
      float w = p.z - p.x, h = p.w - p.y;
      float cx = p.x + 0.5f * w, cy = p.y + 0.5f * h;
      float dx = (a4 + bb4) * 0.1f;
      float dy = (a5 + bb5) * 0.1f;
      float dw = fminf((a6 + bb6) * 0.2f, BBOX_CLIP);
      float dh = fminf((a7 + bb7) * 0.2f, BBOX_CLIP);
      float pcx = fmaf(dx, w, cx), pcy = fmaf(dy, h, cy);
      float pw = __expf(dw) * w, ph = __expf(dh) * h;
      float x1 = fminf(fmaxf(pcx - 0.5f * pw, 0.f), IMG);
      float y1 = fminf(fmaxf(pcy - 0.5f * ph, 0.f), IMG);
      float x2 = fminf(fmaxf(pcx + 0.5f * pw, 0.f), IMG);
      float y2 = fminf(fmaxf(pcy + 0.5f * ph, 0.f), IMG);

      size_t ob = (size_t)row * 5;
      out[ob + 0] = x1;
      out[ob + 1] = y1;
      out[ob + 2] = x2;
      out[ob + 3] = y2;
      ws_scores[row] = sth;
      ((float4*)ws_boxes)[row] = make_float4(x1, y1, x2, y2);
    }
  }
}

// ---------------------------------------------------------------------------
// u64 max with DPP row_ror (VALU-latency cross-lane). After ror 1,2,4,8 every
// lane holds the max of its 16-lane row. Zero-fill never occurs for row_ror
// (pure rotation), and all real keys > 0 anyway.
// ---------------------------------------------------------------------------
template <int CTRL>
__device__ __forceinline__ ull dpp_max_u64(ull k) {
  int lo = __builtin_amdgcn_update_dpp(0, (int)(unsigned)k, CTRL, 0xF, 0xF, true);
  int hi = __builtin_amdgcn_update_dpp(0, (int)(unsigned)(k >> 32), CTRL, 0xF, 0xF, true);
  ull o = ((ull)(unsigned)hi << 32) | (unsigned)lo;
  return o > k ? o : k;
}

__device__ __forceinline__ ull read_lane_u64(ull v, int lane) {
  unsigned lo = (unsigned)__builtin_amdgcn_readlane((int)(unsigned)v, lane);
  unsigned hi = (unsigned)__builtin_amdgcn_readlane((int)(v >> 32), lane);
  return ((ull)hi << 32) | lo;
}

// ---------------------------------------------------------------------------
// Kernel 2: greedy NMS, one 512-thread block (8 waves) per batch image.
// Row n = k*512 + t, 8 slots/thread, all state VGPR-resident:
//   key[8] = (score_bits<<32) | ~n   (suppress = zero the high word)
//   box[8], areaE[8] (area + 1e-9)
// Max key == reference argmax (first-index tie-break via ~n); sentinels
// (n>=4000) have high=0 and lose to every real row incl. (0,~0) -> the
// all-suppressed case picks row 0 with valid=false (keep-revocation exact).
// Per-wave winner {key,box} published to LDS by the owning thread (found via
// 4 DPP ror stages + 4 readlanes + scalar max). Next iter: read 8 keys
// (broadcast), max-combine, decode owner wave FROM the key (wave=(n>>6)&7),
// one dependent broadcast box read. One barrier/iter, double-buffered.
// ---------------------------------------------------------------------------
__global__ __launch_bounds__(512, 2) void nms_kernel(
    const float* __restrict__ ws_scores, const float* __restrict__ ws_boxes,
    float* __restrict__ out) {
  const int b = blockIdx.x;
  const int t = threadIdx.x;  // 0..511
  const int wave = t >> 6;
  const int lane = t & 63;

  __shared__ ull Lkey[2][8];
  __shared__ float4 LboxW[2][8];

  const float* sc = ws_scores + (size_t)b * kN;
  const float4* bx = (const float4*)ws_boxes + (size_t)b * kN;

  ull key[8];
  float areaE[8];
  float4 box[8];
  unsigned keep_mask = 0u;
  const unsigned nt = ~(unsigned)t;  // slot k low word = nt - (k<<9)

#pragma unroll
  for (int k = 0; k < 8; ++k) {
    int n = k * 512 + t;
    unsigned lo = nt - (unsigned)(k << 9);
    if (n < kN) {
      box[k] = bx[n];
      key[k] = ((ull)__float_as_uint(sc[n]) << 32) | lo;  // scores >= 0
      areaE[k] = fmaxf(box[k].z - box[k].x, 0.f) *
                     fmaxf(box[k].w - box[k].y, 0.f) +
                 1e-9f;
    } else {
      box[k] = make_float4(0.f, 0.f, 0.f, 0.f);
      key[k] = (ull)lo;  // high word 0: loses to all real rows
      areaE[k] = 1e-9f;
    }
  }

  auto reduce_publish = [&](int parity) {
    ull m = key[0];
#pragma unroll
    for (int k = 1; k < 8; ++k) m = key[k] > m ? key[k] : m;
    const ull lk = m;  // this thread's local winner
    m = dpp_max_u64<0x121>(m);
    m = dpp_max_u64<0x122>(m);
    m = dpp_max_u64<0x124>(m);
    m = dpp_max_u64<0x128>(m);  // all lanes: 16-lane row max
    ull r0 = read_lane_u64(m, 0);
    ull r1 = read_lane_u64(m, 16);
    ull r2 = read_lane_u64(m, 32);
    ull r3 = read_lane_u64(m, 48);
    r0 = r1 > r0 ? r1 : r0;
    r2 = r3 > r2 ? r3 : r2;
    r0 = r2 > r0 ? r2 : r0;  // wave max, uniform (SGPR)
    if (lk == r0) {           // exactly one thread per wave (keys unique)
      unsigned n = ~(unsigned)r0;
      int slot = n >> 9;
      float4 sb = box[0];
#pragma unroll
      for (int k = 1; k < 8; ++k) sb = (slot == k) ? box[k] : sb;
      Lkey[parity][wave] = r0;
      LboxW[parity][wave] = sb;
    }
  };

  reduce_publish(1);  // loop it=0 reads parity (0+1)&1 = 1
  __syncthreads();

  for (int it = 0; it < MAXDET; ++it) {
    const int pr = (it + 1) & 1;
    ull k0 = Lkey[pr][0], k1 = Lkey[pr][1], k2 = Lkey[pr][2], k3 = Lkey[pr][3];
    ull k4 = Lkey[pr][4], k5 = Lkey[pr][5], k6 = Lkey[pr][6], k7 = Lkey[pr][7];
    k0 = k1 > k0 ? k1 : k0;
    k2 = k3 > k2 ? k3 : k2;
    k4 = k5 > k4 ? k5 : k4;
    k6 = k7 > k6 ? k7 : k6;
    k0 = k2 > k0 ? k2 : k0;
    k4 = k6 > k4 ? k6 : k4;
    k0 = k4 > k0 ? k4 : k0;  // block winner key (uniform)
    const unsigned whi = (unsigned)__builtin_amdgcn_readfirstlane((int)(k0 >> 32));
    const unsigned wlo = (unsigned)__builtin_amdgcn_readfirstlane((int)(unsigned)k0);
    const unsigned wn = ~wlo;            // winner row < kN
    const bool valid = whi != 0u;
    const int wwave = (int)((wn >> 6) & 7);  // owner wave from row index
    const float4 wb = LboxW[pr][wwave];      // broadcast read
    const float wa = fmaxf(wb.z - wb.x, 0.f) * fmaxf(wb.w - wb.y, 0.f);
    const bool iOwn = ((unsigned)t == (wn & 511u));
    const int oSlot = (int)(wn >> 9);
    if (iOwn) {
      unsigned bit = 1u << oSlot;
      keep_mask = valid ? (keep_mask | bit) : (keep_mask & ~bit);
    }
#pragma unroll
    for (int k = 0; k < 8; ++k) {
      float dx = fminf(wb.z, box[k].z) - fmaxf(wb.x, box[k].x);
      float dy = fminf(wb.w, box[k].w) - fmaxf(wb.y, box[k].y);
      float inter3 = 3.0f * fmaxf(dx, 0.f) * fmaxf(dy, 0.f);
      // iou > 0.5  <=>  3*inter > wa + area + 1e-9
      bool clr = (inter3 > wa + areaE[k]) || (iOwn && k == oSlot);
      if (clr) key[k] &= 0xFFFFFFFFull;  // zero score word, keep ~n
    }
    reduce_publish(it & 1);
    __syncthreads();
  }

#pragma unroll
  for (int k = 0; k < 8; ++k) {
    int n = k * 512 + t;
    if (n < kN) {
      out[((size_t)(b * kN + n)) * 5 + 4] =
          (keep_mask >> k) & 1u ? sc[n] : 0.0f;
    }
  }
}

extern "C" void kernel_launch(void* const* d_in, const int* in_sizes, int n_in,
                              void* d_out, int out_size, void* d_ws,
                              size_t ws_size, hipStream_t stream) {
  const float* feats = (const float*)d_in[0];      // (16,4000,1024)
  const float* proposals = (const float*)d_in[1];  // (16,4000,4)
  const float* Wc = (const float*)d_in[2];         // (2,1024)
  const float* bc = (const float*)d_in[3];         // (2,)
  const float* Wb = (const float*)d_in[4];         // (8,1024)
  const float* bb = (const float*)d_in[5];         // (8,)
  float* out = (float*)d_out;                      // (16,4000,5)

  float* ws_scores = (float*)d_ws;        // 64000 floats
  float* ws_boxes = ws_scores + kB * kN;  // 64000*4 floats, 16B aligned

  head_kernel<<<512, 256, 0, stream>>>(feats, proposals, Wc, bc, Wb, bb, out,
                                       ws_scores, ws_boxes);
  nms_kernel<<<kB, 512, 0, stream>>>(ws_scores, ws_boxes, out);
}

// Round 6
// 452.168 us; speedup vs baseline: 1.5971x; 1.5971x over previous
//
#include <hip/hip_runtime.h>
#include <math.h>

#define IMG 800.0f
#define SCORE_TH 0.25f
#define NMS_TH 0.5f
#define MAXDET 100
#define BBOX_CLIP 4.135166556742356f /* log(1000/16) */

constexpr int kB = 16;
constexpr int kN = 4000;
constexpr int kD = 1024;

// ---------------------------------------------------------------------------
// DPP wave-sum: row_shr scan (1,2,4,8) + row_bcast15/31. Full 64-lane sum
// lands in lane 63. Pure VALU — no ds_bpermute / LDS-pipe traffic.
// bound_ctrl=true: out-of-row source lanes contribute 0.0f (safe for sum).
// ---------------------------------------------------------------------------
template <int CTRL>
__device__ __forceinline__ float dpp_add_f32(float v) {
  int s = __builtin_amdgcn_update_dpp(0, __float_as_int(v), CTRL, 0xF, 0xF, true);
  return v + __int_as_float(s);
}

__device__ __forceinline__ float wave_sum_lane63(float v) {
  v = dpp_add_f32<0x111>(v);  // row_shr:1
  v = dpp_add_f32<0x112>(v);  // row_shr:2
  v = dpp_add_f32<0x114>(v);  // row_shr:4
  v = dpp_add_f32<0x118>(v);  // row_shr:8   (lane 16r+15 = row r sum)
  v = dpp_add_f32<0x142>(v);  // row_bcast15 (lane 63 += row2 sum via lane47)
  v = dpp_add_f32<0x143>(v);  // row_bcast31 (lane 63 += rows0+1 via lane31)
  return v;                   // lane 63: full wave sum
}

// ---------------------------------------------------------------------------
// Kernel 1: fused head matmul (6 needed channels only) + softmax + box decode.
// One wave per row; per-lane weight slice in registers; DPP-based reduction
// (round 5: the 36 shfl_xor/row = ds_bpermute ops contended the LDS pipe).
// ---------------------------------------------------------------------------
__global__ __launch_bounds__(256, 2) void head_kernel(
    const float* __restrict__ feats, const float* __restrict__ proposals,
    const float* __restrict__ Wc, const float* __restrict__ bc,
    const float* __restrict__ Wb, const float* __restrict__ bb,
    float* __restrict__ out, float* __restrict__ ws_scores,
    float* __restrict__ ws_boxes) {
  const int lane = threadIdx.x & 63;
  const int waveId = (blockIdx.x * blockDim.x + threadIdx.x) >> 6;
  const int nWaves = (gridDim.x * blockDim.x) >> 6;

  const float4* Wc4 = (const float4*)Wc;  // (2,1024) -> 2*256 float4
  const float4* Wb4 = (const float4*)Wb;  // (8,1024) -> 8*256 float4
  float4 w0[4], w1[4], w4[4], w5[4], w6[4], w7[4];
#pragma unroll
  for (int ch = 0; ch < 4; ++ch) {
    int idx = ch * 64 + lane;
    w0[ch] = Wc4[0 * 256 + idx];
    w1[ch] = Wc4[1 * 256 + idx];
    w4[ch] = Wb4[4 * 256 + idx];
    w5[ch] = Wb4[5 * 256 + idx];
    w6[ch] = Wb4[6 * 256 + idx];
    w7[ch] = Wb4[7 * 256 + idx];
  }
  const float bc0 = bc[0], bc1 = bc[1];
  const float bb4 = bb[4], bb5 = bb[5], bb6 = bb[6], bb7 = bb[7];

  const int R = kB * kN;
  for (int row = waveId; row < R; row += nWaves) {
    const float4* F = (const float4*)(feats + (size_t)row * kD);
    float a0 = 0.f, a1 = 0.f, a4 = 0.f, a5 = 0.f, a6 = 0.f, a7 = 0.f;
#pragma unroll
    for (int ch = 0; ch < 4; ++ch) {
      float4 f = F[ch * 64 + lane];
      a0 = fmaf(f.x, w0[ch].x, fmaf(f.y, w0[ch].y, fmaf(f.z, w0[ch].z, fmaf(f.w, w0[ch].w, a0))));
      a1 = fmaf(f.x, w1[ch].x, fmaf(f.y, w1[ch].y, fmaf(f.z, w1[ch].z, fmaf(f.w, w1[ch].w, a1))));
      a4 = fmaf(f.x, w4[ch].x, fmaf(f.y, w4[ch].y, fmaf(f.z, w4[ch].z, fmaf(f.w, w4[ch].w, a4))));
      a5 = fmaf(f.x, w5[ch].x, fmaf(f.y, w5[ch].y, fmaf(f.z, w5[ch].z, fmaf(f.w, w5[ch].w, a5))));
      a6 = fmaf(f.x, w6[ch].x, fmaf(f.y, w6[ch].y, fmaf(f.z, w6[ch].z, fmaf(f.w, w6[ch].w, a6))));
      a7 = fmaf(f.x, w7[ch].x, fmaf(f.y, w7[ch].y, fmaf(f.z, w7[ch].z, fmaf(f.w, w7[ch].w, a7))));
    }
    a0 = wave_sum_lane63(a0);
    a1 = wave_sum_lane63(a1);
    a4 = wave_sum_lane63(a4);
    a5 = wave_sum_lane63(a5);
    a6 = wave_sum_lane63(a6);
    a7 = wave_sum_lane63(a7);
    if (lane == 63) {
      float l0 = a0 + bc0, l1 = a1 + bc1;
      float score = 1.0f / (1.0f + __expf(l0 - l1));
      float sth = score > SCORE_TH ? score : 0.0f;

      float4 p = ((const float4*)proposals)[row];
      float w = p.z - p.x, h = p.w - p.y;
      float cx = p.x + 0.5f * w, cy = p.y + 0.5f * h;
      float dx = (a4 + bb4) * 0.1f;
      float dy = (a5 + bb5) * 0.1f;
      float dw = fminf((a6 + bb6) * 0.2f, BBOX_CLIP);
      float dh = fminf((a7 + bb7) * 0.2f, BBOX_CLIP);
      float pcx = fmaf(dx, w, cx), pcy = fmaf(dy, h, cy);
      float pw = __expf(dw) * w, ph = __expf(dh) * h;
      float x1 = fminf(fmaxf(pcx - 0.5f * pw, 0.f), IMG);
      float y1 = fminf(fmaxf(pcy - 0.5f * ph, 0.f), IMG);
      float x2 = fminf(fmaxf(pcx + 0.5f * pw, 0.f), IMG);
      float y2 = fminf(fmaxf(pcy + 0.5f * ph, 0.f), IMG);

      size_t ob = (size_t)row * 5;
      out[ob + 0] = x1;
      out[ob + 1] = y1;
      out[ob + 2] = x2;
      out[ob + 3] = y2;
      ws_scores[row] = sth;
      ((float4*)ws_boxes)[row] = make_float4(x1, y1, x2, y2);
    }
  }
}

// ---------------------------------------------------------------------------
// DPP-based wave argmax on packed u64 keys (r4 version — VGPR-happy, 93 µs;
// r5's 512-thread ull-array variant spilled to scratch: VGPR 40, +2 MB spill
// traffic, 370 µs. Do not restructure without disasm evidence.)
// ---------------------------------------------------------------------------
template <int CTRL>
__device__ __forceinline__ unsigned long long dpp_max_u64(unsigned long long k) {
  int lo = __builtin_amdgcn_update_dpp(0, (int)(unsigned)k, CTRL, 0xF, 0xF, true);
  int hi =
      __builtin_amdgcn_update_dpp(0, (int)(unsigned)(k >> 32), CTRL, 0xF, 0xF, true);
  unsigned long long o = ((unsigned long long)(unsigned)hi << 32) | (unsigned)lo;
  return o > k ? o : k;
}

__device__ __forceinline__ unsigned long long wave_max_u64(unsigned long long k) {
  k = dpp_max_u64<0x121>(k);  // row_ror:1
  k = dpp_max_u64<0x122>(k);  // row_ror:2
  k = dpp_max_u64<0x124>(k);  // row_ror:4
  k = dpp_max_u64<0x128>(k);  // row_ror:8   (every lane: 16-lane row max)
  k = dpp_max_u64<0x142>(k);  // row_bcast15 (rows 1,3 pick up rows 0,2)
  k = dpp_max_u64<0x143>(k);  // row_bcast31 (lane 63: wave max)
  return k;
}

// ---------------------------------------------------------------------------
// Kernel 2: greedy NMS, one 256-thread block (4 waves) per batch image.
// Exact r4 kernel (measured ~93 µs): khi[16]/areaE[16]/box[16] per thread,
// Lbox mirror in LDS, key=(score_bits<<32)|~n, one barrier/iter,
// double-buffered leader keys.
// ---------------------------------------------------------------------------
__global__ __launch_bounds__(256, 1) void nms_kernel(
    const float* __restrict__ ws_scores, const float* __restrict__ ws_boxes,
    float* __restrict__ out) {
  const int b = blockIdx.x;
  const int t = threadIdx.x;  // 0..255
  const int wave = t >> 6;
  const int lane = t & 63;

  __shared__ float4 Lbox[kN];              // 64000 B
  __shared__ unsigned long long Lkey[2][4];

  const float* sc = ws_scores + (size_t)b * kN;
  const float4* bx = (const float4*)ws_boxes + (size_t)b * kN;

  unsigned khi[16];
  float areaE[16];  // area + 1e-9
  float4 box[16];
  unsigned keep_mask = 0u;
  const unsigned nt = ~(unsigned)t;  // slot k low word = nt - 256k

#pragma unroll
  for (int k = 0; k < 16; ++k) {
    int n = k * 256 + t;
    if (n < kN) {
      box[k] = bx[n];
      khi[k] = __float_as_uint(sc[n]);  // scores >= 0: bits monotone
      areaE[k] = fmaxf(box[k].z - box[k].x, 0.f) *
                     fmaxf(box[k].w - box[k].y, 0.f) +
                 1e-9f;
      Lbox[n] = box[k];
    } else {
      box[k] = make_float4(0.f, 0.f, 0.f, 0.f);  // inter==0 vs any real box
      khi[k] = 0u;
      areaE[k] = 1e-9f;
    }
  }

  auto reduce_publish = [&](int parity) {
    unsigned long long lk[16];
#pragma unroll
    for (int k = 0; k < 16; ++k)
      lk[k] = ((unsigned long long)khi[k] << 32) |
              (unsigned long long)(nt - (unsigned)(k * 256));
#pragma unroll
    for (int k = 0; k < 8; ++k) lk[k] = lk[k] > lk[k + 8] ? lk[k] : lk[k + 8];
#pragma unroll
    for (int k = 0; k < 4; ++k) lk[k] = lk[k] > lk[k + 4] ? lk[k] : lk[k + 4];
    lk[0] = lk[0] > lk[2] ? lk[0] : lk[2];
    lk[1] = lk[1] > lk[3] ? lk[1] : lk[3];
    lk[0] = lk[0] > lk[1] ? lk[0] : lk[1];
    unsigned long long wkey = wave_max_u64(lk[0]);
    if (lane == 63) Lkey[parity][wave] = wkey;
  };

  reduce_publish(1);  // loop it=0 reads parity (0+1)&1 = 1
  __syncthreads();

  for (int it = 0; it < MAXDET; ++it) {
    const int pr = (it + 1) & 1;
    unsigned long long wk = Lkey[pr][0];
    unsigned long long k1 = Lkey[pr][1];
    unsigned long long k2 = Lkey[pr][2];
    unsigned long long k3 = Lkey[pr][3];
    wk = wk > k1 ? wk : k1;
    k2 = k2 > k3 ? k2 : k3;
    wk = wk > k2 ? wk : k2;
    // Uniform across the block -> scalarize the decode.
    const unsigned whi = (unsigned)__builtin_amdgcn_readfirstlane((int)(wk >> 32));
    const unsigned wlo = (unsigned)__builtin_amdgcn_readfirstlane((int)(unsigned)wk);
    const unsigned wn = ~wlo;  // winner row, always < kN
    const bool valid = whi != 0u;
    const float4 wb = Lbox[wn];  // broadcast read
    const float wa = fmaxf(wb.z - wb.x, 0.f) * fmaxf(wb.w - wb.y, 0.f);
    const bool iOwn = ((unsigned)t == (wn & 255u));
    const int oSlot = (int)(wn >> 8);
    if (iOwn) {
      unsigned bit = 1u << oSlot;
      keep_mask = valid ? (keep_mask | bit) : (keep_mask & ~bit);
    }
#pragma unroll
    for (int k = 0; k < 16; ++k) {
      float dx = fminf(wb.z, box[k].z) - fmaxf(wb.x, box[k].x);
      float dy = fminf(wb.w, box[k].w) - fmaxf(wb.y, box[k].y);
      float inter3 = 3.0f * fmaxf(dx, 0.f) * fmaxf(dy, 0.f);
      // iou > 0.5  <=>  3*inter > wa + area + 1e-9
      bool sup = inter3 > wa + areaE[k];
      if (sup || (iOwn && k == oSlot)) khi[k] = 0u;
    }
    reduce_publish(it & 1);
    __syncthreads();
  }

#pragma unroll
  for (int k = 0; k < 16; ++k) {
    int n = k * 256 + t;
    if (n < kN) {
      out[((size_t)(b * kN + n)) * 5 + 4] =
          (keep_mask >> k) & 1u ? sc[n] : 0.0f;
    }
  }
}

extern "C" void kernel_launch(void* const* d_in, const int* in_sizes, int n_in,
                              void* d_out, int out_size, void* d_ws,
                              size_t ws_size, hipStream_t stream) {
  const float* feats = (const float*)d_in[0];      // (16,4000,1024)
  const float* proposals = (const float*)d_in[1];  // (16,4000,4)
  const float* Wc = (const float*)d_in[2];         // (2,1024)
  const float* bc = (const float*)d_in[3];         // (2,)
  const float* Wb = (const float*)d_in[4];         // (8,1024)
  const float* bb = (const float*)d_in[5];         // (8,)
  float* out = (float*)d_out;                      // (16,4000,5)

  float* ws_scores = (float*)d_ws;        // 64000 floats
  float* ws_boxes = ws_scores + kB * kN;  // 64000*4 floats, 16B aligned

  head_kernel<<<512, 256, 0, stream>>>(feats, proposals, Wc, bc, Wb, bb, out,
                                       ws_scores, ws_boxes);
  nms_kernel<<<kB, 256, 0, stream>>>(ws_scores, ws_boxes, out);
}